// Round 3
// baseline (58.382 us; speedup 1.0000x reference)
//
#include <hip/hip_runtime.h>
#include <hip/hip_cooperative_groups.h>
#include <math.h>

namespace cg = cooperative_groups;

#define NB 8
#define NQ 32
#define NK 32
#define DIM 256

struct c32 { float x, y; };
__device__ __forceinline__ c32 cmul(c32 a, c32 b) {
    return { a.x*b.x - a.y*b.y, a.x*b.y + a.y*b.x };
}

// ---------------------------------------------------------------------------
// Compile-time GF(2) bookkeeping for the CNOT layers.
// Each rep's 8-CNOT layer is a linear map L on index bits: new[x] = old[L x].
// We never move data; we track M (logical->stored) and Minv.
//   - gate on logical bit b pairs stored indices {x, x ^ M(e_b)}
//   - "bit=1" role of stored x is parity(x & row_b(Minv))
//   - final store: logical index of stored x is Minv(x)
// ---------------------------------------------------------------------------
struct Maps { unsigned char m[6][8]; unsigned char r[6][8]; unsigned char fin[8]; };

constexpr unsigned gstep(int rep, unsigned y, int i) {
    int tgt = (i + 1 + rep) % 8;
    return y ^ (((y >> (7 - i)) & 1u) << (7 - tgt));
}
constexpr unsigned Lmap(int rep, unsigned x) {   // verified: matches round-2 perm loop
    unsigned y = x;
    for (int i = 7; i >= 0; --i) y = gstep(rep, y, i);
    return y;
}
constexpr unsigned Linvmap(int rep, unsigned x) {
    unsigned y = x;
    for (int i = 0; i < 8; ++i) y = gstep(rep, y, i);
    return y;
}
constexpr Maps make_maps() {
    Maps mp{};
    unsigned Mc[8], Mic[8];
    for (int j2 = 0; j2 < 8; ++j2) { Mc[j2] = 1u << j2; Mic[j2] = 1u << j2; }
    for (int rep = 0; rep < 6; ++rep) {
        for (int bb = 0; bb < 8; ++bb) {
            mp.m[rep][bb] = (unsigned char)Mc[bb];
            unsigned row = 0;
            for (int k = 0; k < 8; ++k) row |= ((Mic[k] >> bb) & 1u) << k;
            mp.r[rep][bb] = (unsigned char)row;
        }
        unsigned nM[8], nMi[8];
        for (int j2 = 0; j2 < 8; ++j2) {
            unsigned v = Lmap(rep, 1u << j2), acc = 0;
            for (int k = 0; k < 8; ++k) if ((v >> k) & 1u) acc ^= Mc[k];
            nM[j2]  = acc;                       // M_new = M o L
            nMi[j2] = Linvmap(rep, Mic[j2]);     // Minv_new = Linv o Minv
        }
        for (int j2 = 0; j2 < 8; ++j2) { Mc[j2] = nM[j2]; Mic[j2] = nMi[j2]; }
    }
    for (int j2 = 0; j2 < 8; ++j2) mp.fin[j2] = (unsigned char)Mic[j2];
    return mp;
}
constexpr Maps MAPS = make_maps();

// ---------------------------------------------------------------------------
// One cooperative kernel: phase A (v-sim on wave0, U-build on wave1, attn
// coeffs on wave2) -> grid.sync -> phase B (weighted sum + expectation).
// blockIdx = b*32 + j ; j = k-state in phase A, q-row in phase B.
// ---------------------------------------------------------------------------
__global__ __launch_bounds__(256) void fused_kernel(
        const float* __restrict__ query, const float* __restrict__ key,
        const float* __restrict__ value, const float* __restrict__ v_param,
        const float* __restrict__ qk_param, const float* __restrict__ attn_param,
        float2* __restrict__ vs, float* __restrict__ out) {
    __shared__ float2 U[48][4];
    __shared__ float2 coeff[32];
    __shared__ float2 totsh;
    __shared__ float prob[256];

    const int s  = blockIdx.x;
    const int b  = s >> 5;
    const int j  = s & 31;
    const int t  = threadIdx.x;
    const int wv = t >> 6;
    const int ln = t & 63;

    float2 amp[4];

    // ---- phase A setup (parallel across waves) ----
    if (wv == 1 && ln < 48) {                 // U matrices (state-independent)
        int rep = ln >> 3, w = ln & 7;
        float a   = v_param[(rep*3 + 0)*8 + w];
        float bb2 = v_param[(rep*3 + 1)*8 + w];
        float c   = v_param[(rep*3 + 2)*8 + w];
        float sb, cb;     __sincosf(bb2*0.5f, &sb, &cb);
        float sapc, capc; __sincosf((a + c)*0.5f, &sapc, &capc);
        float samc, camc; __sincosf((a - c)*0.5f, &samc, &camc);
        U[ln][0] = make_float2( cb*capc, -cb*sapc);
        U[ln][1] = make_float2(-sb*camc, -sb*samc);
        U[ln][2] = make_float2( sb*camc, -sb*samc);
        U[ln][3] = make_float2( cb*capc,  cb*sapc);
    }
    if (wv == 2 && ln < 32) {                 // attn factors + suffix scan
        const int k = ln;
        c32 f = { 1.f, 0.f };
        #pragma unroll
        for (int i = 0; i < 8; ++i) {
            float qi  = query[(b*NQ + j)*8 + i];
            float ki  = key[(b*NK + k)*8 + i];
            float phi = attn_param[i] + ((i > 0) ? attn_param[8 + i - 1] : 0.f);
            float Th  = phi + qk_param[8 + i] - ki;
            float gam = qk_param[i] * 0.5f;
            c32 fi = {  __cosf(gam) * __cosf((Th + qi)*0.5f),
                       -__sinf(gam) * __cosf((Th - qi)*0.5f) };
            f = cmul(f, fi);
        }
        float h7 = attn_param[15] * 0.5f;
        float s7 = __sinf(h7), c7 = __cosf(h7);
        c32 a0 = { -s7*f.x, -s7*f.y };
        c32 a1 = {  c7*f.x,  c7*f.y };
        c32 acc = a0;                          // backward inclusive product scan
        #pragma unroll
        for (int off = 1; off < 32; off <<= 1) {
            c32 v = { __shfl_down(acc.x, off), __shfl_down(acc.y, off) };
            if (k + off < 32) acc = cmul(acc, v);
        }
        c32 S = { __shfl_down(acc.x, 1), __shfl_down(acc.y, 1) };
        if (k == 31) { S.x = 1.f; S.y = 0.f; }
        c32 cf = cmul(S, a1);
        coeff[k] = make_float2(cf.x, cf.y);
        if (k == 0) totsh = make_float2(acc.x, acc.y);
    }
    if (wv == 0) {                            // initial RY product state
        float cv[8], sv[8];
        #pragma unroll
        for (int i = 0; i < 8; ++i) __sincosf(value[s*8 + i]*0.5f, &sv[i], &cv[i]);
        float common = 1.f;
        #pragma unroll
        for (int i = 0; i < 6; ++i)
            common *= ((ln >> (5 - i)) & 1) ? sv[i] : cv[i];
        amp[0] = make_float2(common*cv[6]*cv[7], 0.f);
        amp[1] = make_float2(common*cv[6]*sv[7], 0.f);
        amp[2] = make_float2(common*sv[6]*cv[7], 0.f);
        amp[3] = make_float2(common*sv[6]*sv[7], 0.f);
    }
    __syncthreads();                          // publish U

    // ---- phase A: 48-gate chain, barrier-free (virtual permutations) ----
    if (wv == 0) {
        #pragma unroll
        for (int rep = 0; rep < 6; ++rep) {
            #pragma unroll
            for (int w = 0; w < 8; ++w) {
                const int g = rep*8 + w;
                const unsigned mm = MAPS.m[rep][7 - w];
                const unsigned rb = MAPS.r[rep][7 - w];
                const unsigned lm = mm >> 2;
                const unsigned sm = mm & 3;
                const float2 u00 = U[g][0], u01 = U[g][1];
                const float2 u10 = U[g][2], u11 = U[g][3];
                float2 P[4];
                if (sm == 0)      { P[0]=amp[0]; P[1]=amp[1]; P[2]=amp[2]; P[3]=amp[3]; }
                else if (sm == 1) { P[0]=amp[1]; P[1]=amp[0]; P[2]=amp[3]; P[3]=amp[2]; }
                else if (sm == 2) { P[0]=amp[2]; P[1]=amp[3]; P[2]=amp[0]; P[3]=amp[1]; }
                else              { P[0]=amp[3]; P[1]=amp[2]; P[2]=amp[1]; P[3]=amp[0]; }
                if (lm) {
                    #pragma unroll
                    for (int r2 = 0; r2 < 4; ++r2) {
                        P[r2].x = __shfl_xor(P[r2].x, (int)lm);
                        P[r2].y = __shfl_xor(P[r2].y, (int)lm);
                    }
                }
                const unsigned hx = __popc((unsigned)(ln << 2) & rb) & 1u;
                float2 na[4];
                #pragma unroll
                for (int r2 = 0; r2 < 4; ++r2) {
                    const bool h = (hx ^ (__popc((unsigned)r2 & rb) & 1u)) != 0u;
                    const float2 uo = h ? u11 : u00;   // coeff of own amp
                    const float2 up = h ? u10 : u01;   // coeff of partner amp
                    na[r2].x = uo.x*amp[r2].x - uo.y*amp[r2].y + up.x*P[r2].x - up.y*P[r2].y;
                    na[r2].y = uo.x*amp[r2].y + uo.y*amp[r2].x + up.x*P[r2].y + up.y*P[r2].x;
                }
                #pragma unroll
                for (int r2 = 0; r2 < 4; ++r2) amp[r2] = na[r2];
            }
        }
        // scatter-store through Minv_final to logical order
        unsigned c0 = 0;
        #pragma unroll
        for (int kk = 0; kk < 6; ++kk)
            c0 ^= ((ln >> kk) & 1) ? (unsigned)MAPS.fin[kk + 2] : 0u;
        float2* base = vs + (size_t)s * DIM;
        #pragma unroll
        for (int r2 = 0; r2 < 4; ++r2) {
            unsigned c = c0 ^ ((r2 & 1) ? (unsigned)MAPS.fin[0] : 0u)
                            ^ ((r2 & 2) ? (unsigned)MAPS.fin[1] : 0u);
            base[c] = amp[r2];
        }
    }

    cg::this_grid().sync();

    // ---- phase B: v_new, probs, sign expectation ----
    {
        const int d = t;
        const float2* vb = vs + (size_t)(b * NK) * DIM;
        c32 vn = { 0.f, 0.f };
        #pragma unroll 8
        for (int k = 0; k < 32; ++k) {
            float2 cf = coeff[k];
            float2 v  = vb[k*DIM + d];
            vn.x += cf.x*v.x - cf.y*v.y;
            vn.y += cf.x*v.y + cf.y*v.x;
        }
        if (d == 0) { vn.x += totsh.x; vn.y += totsh.y; }
        prob[d] = vn.x*vn.x + vn.y*vn.y;
    }
    __syncthreads();
    {
        const int gg = t >> 5, l = t & 31;
        float sp = 0.f, ss = 0.f;
        #pragma unroll
        for (int j2 = 0; j2 < 8; ++j2) {
            int d2 = l + 32*j2;
            float p = prob[d2];
            sp += p;
            ss += ((d2 >> (7 - gg)) & 1) ? -p : p;
        }
        #pragma unroll
        for (int off = 1; off < 32; off <<= 1) {
            sp += __shfl_xor(sp, off);
            ss += __shfl_xor(ss, off);
        }
        if (l == 0) out[(b*NQ + j)*8 + gg] = ss / sp;
    }
}

extern "C" void kernel_launch(void* const* d_in, const int* in_sizes, int n_in,
                              void* d_out, int out_size, void* d_ws, size_t ws_size,
                              hipStream_t stream) {
    const float* query      = (const float*)d_in[0];
    const float* key        = (const float*)d_in[1];
    const float* value      = (const float*)d_in[2];
    const float* v_param    = (const float*)d_in[3];
    const float* qk_param   = (const float*)d_in[4];
    const float* attn_param = (const float*)d_in[5];
    float2* vs = (float2*)d_ws;   // 256 states x 256 complex = 512 KB scratch
    float* out = (float*)d_out;

    void* args[] = { &query, &key, &value, &v_param, &qk_param, &attn_param, &vs, &out };
    hipLaunchCooperativeKernel((void*)fused_kernel, dim3(NB*NK), dim3(256),
                               args, 0, stream);
}

// Round 4
// 43.932 us; speedup vs baseline: 1.3289x; 1.3289x over previous
//
#include <hip/hip_runtime.h>
#include <math.h>

#define NB 8
#define NQ 32
#define NK 32
#define DIM 256

struct c32 { float x, y; };
__device__ __forceinline__ c32 cmul(c32 a, c32 b) {
    return { a.x*b.x - a.y*b.y, a.x*b.y + a.y*b.x };
}

// ---------------------------------------------------------------------------
// Compile-time GF(2) bookkeeping for the CNOT layers (verified round 3).
// ---------------------------------------------------------------------------
struct Maps { unsigned char m[6][8]; unsigned char r[6][8]; unsigned char fin[8]; };

constexpr unsigned gstep(int rep, unsigned y, int i) {
    int tgt = (i + 1 + rep) % 8;
    return y ^ (((y >> (7 - i)) & 1u) << (7 - tgt));
}
constexpr unsigned Lmap(int rep, unsigned x) {
    unsigned y = x;
    for (int i = 7; i >= 0; --i) y = gstep(rep, y, i);
    return y;
}
constexpr unsigned Linvmap(int rep, unsigned x) {
    unsigned y = x;
    for (int i = 0; i < 8; ++i) y = gstep(rep, y, i);
    return y;
}
constexpr Maps make_maps() {
    Maps mp{};
    unsigned Mc[8], Mic[8];
    for (int j2 = 0; j2 < 8; ++j2) { Mc[j2] = 1u << j2; Mic[j2] = 1u << j2; }
    for (int rep = 0; rep < 6; ++rep) {
        for (int bb = 0; bb < 8; ++bb) {
            mp.m[rep][bb] = (unsigned char)Mc[bb];
            unsigned row = 0;
            for (int k = 0; k < 8; ++k) row |= ((Mic[k] >> bb) & 1u) << k;
            mp.r[rep][bb] = (unsigned char)row;
        }
        unsigned nM[8], nMi[8];
        for (int j2 = 0; j2 < 8; ++j2) {
            unsigned v = Lmap(rep, 1u << j2), acc = 0;
            for (int k = 0; k < 8; ++k) if ((v >> k) & 1u) acc ^= Mc[k];
            nM[j2]  = acc;
            nMi[j2] = Linvmap(rep, Mic[j2]);
        }
        for (int j2 = 0; j2 < 8; ++j2) { Mc[j2] = nM[j2]; Mic[j2] = nMi[j2]; }
    }
    for (int j2 = 0; j2 < 8; ++j2) mp.fin[j2] = (unsigned char)Mic[j2];
    return mp;
}
constexpr Maps MAPS = make_maps();

// ---------------------------------------------------------------------------
// Single launch, 512 blocks:
//   blocks [0,256):   v-sim producer for state s = blockIdx (release ctr[b])
//   blocks [256,512): attn consumer for (b,q) (acquire-spin on ctr[b]==32)
// ---------------------------------------------------------------------------
__global__ __launch_bounds__(256) void fused_kernel(
        const float* __restrict__ query, const float* __restrict__ key,
        const float* __restrict__ value, const float* __restrict__ v_param,
        const float* __restrict__ qk_param, const float* __restrict__ attn_param,
        float2* __restrict__ vs, unsigned* __restrict__ ctr,
        float* __restrict__ out) {
    const int t  = threadIdx.x;
    const int wv = t >> 6;
    const int ln = t & 63;

    __shared__ float2 U[48][4];
    __shared__ float2 a0s[32], a1s[32], coeff[32];
    __shared__ float2 totsh;
    __shared__ float prob[256];

    if (blockIdx.x < NB * NK) {
        // ================= producer: v-circuit sim for state s =================
        const int s = blockIdx.x;
        const int b = s >> 5;
        float2 amp[4];

        if (wv == 1 && ln < 48) {               // U matrices (state-independent)
            int rep = ln >> 3, w = ln & 7;
            float a   = v_param[(rep*3 + 0)*8 + w];
            float bb2 = v_param[(rep*3 + 1)*8 + w];
            float c   = v_param[(rep*3 + 2)*8 + w];
            float sb, cb;     __sincosf(bb2*0.5f, &sb, &cb);
            float sapc, capc; __sincosf((a + c)*0.5f, &sapc, &capc);
            float samc, camc; __sincosf((a - c)*0.5f, &samc, &camc);
            U[ln][0] = make_float2( cb*capc, -cb*sapc);
            U[ln][1] = make_float2(-sb*camc, -sb*samc);
            U[ln][2] = make_float2( sb*camc, -sb*samc);
            U[ln][3] = make_float2( cb*capc,  cb*sapc);
        }
        if (wv == 0) {                          // initial RY product state
            float cv[8], sv[8];
            #pragma unroll
            for (int i = 0; i < 8; ++i) __sincosf(value[s*8 + i]*0.5f, &sv[i], &cv[i]);
            float common = 1.f;
            #pragma unroll
            for (int i = 0; i < 6; ++i)
                common *= ((ln >> (5 - i)) & 1) ? sv[i] : cv[i];
            amp[0] = make_float2(common*cv[6]*cv[7], 0.f);
            amp[1] = make_float2(common*cv[6]*sv[7], 0.f);
            amp[2] = make_float2(common*sv[6]*cv[7], 0.f);
            amp[3] = make_float2(common*sv[6]*sv[7], 0.f);
        }
        __syncthreads();                        // publish U

        if (wv == 0) {
            // 48-gate chain, barrier-free (virtual permutations; verified r3)
            #pragma unroll
            for (int rep = 0; rep < 6; ++rep) {
                #pragma unroll
                for (int w = 0; w < 8; ++w) {
                    const int g = rep*8 + w;
                    const unsigned mm = MAPS.m[rep][7 - w];
                    const unsigned rb = MAPS.r[rep][7 - w];
                    const unsigned lm = mm >> 2;
                    const unsigned sm = mm & 3;
                    const float2 u00 = U[g][0], u01 = U[g][1];
                    const float2 u10 = U[g][2], u11 = U[g][3];
                    float2 P[4];
                    if (sm == 0)      { P[0]=amp[0]; P[1]=amp[1]; P[2]=amp[2]; P[3]=amp[3]; }
                    else if (sm == 1) { P[0]=amp[1]; P[1]=amp[0]; P[2]=amp[3]; P[3]=amp[2]; }
                    else if (sm == 2) { P[0]=amp[2]; P[1]=amp[3]; P[2]=amp[0]; P[3]=amp[1]; }
                    else              { P[0]=amp[3]; P[1]=amp[2]; P[2]=amp[1]; P[3]=amp[0]; }
                    if (lm) {
                        #pragma unroll
                        for (int r2 = 0; r2 < 4; ++r2) {
                            P[r2].x = __shfl_xor(P[r2].x, (int)lm);
                            P[r2].y = __shfl_xor(P[r2].y, (int)lm);
                        }
                    }
                    const unsigned hx = __popc((unsigned)(ln << 2) & rb) & 1u;
                    float2 na[4];
                    #pragma unroll
                    for (int r2 = 0; r2 < 4; ++r2) {
                        const bool h = (hx ^ (__popc((unsigned)r2 & rb) & 1u)) != 0u;
                        const float2 uo = h ? u11 : u00;
                        const float2 up = h ? u10 : u01;
                        na[r2].x = uo.x*amp[r2].x - uo.y*amp[r2].y + up.x*P[r2].x - up.y*P[r2].y;
                        na[r2].y = uo.x*amp[r2].y + uo.y*amp[r2].x + up.x*P[r2].y + up.y*P[r2].x;
                    }
                    #pragma unroll
                    for (int r2 = 0; r2 < 4; ++r2) amp[r2] = na[r2];
                }
            }
            // scatter-store through Minv_final to logical order
            unsigned c0 = 0;
            #pragma unroll
            for (int kk = 0; kk < 6; ++kk)
                c0 ^= ((ln >> kk) & 1) ? (unsigned)MAPS.fin[kk + 2] : 0u;
            float2* base = vs + (size_t)s * DIM;
            #pragma unroll
            for (int r2 = 0; r2 < 4; ++r2) {
                unsigned c = c0 ^ ((r2 & 1) ? (unsigned)MAPS.fin[0] : 0u)
                                ^ ((r2 & 2) ? (unsigned)MAPS.fin[1] : 0u);
                base[c] = amp[r2];
            }
            __threadfence();                    // make vs visible device-wide
        }
        __syncthreads();
        if (t == 0)
            __hip_atomic_fetch_add(&ctr[b*16], 1u, __ATOMIC_RELEASE,
                                   __HIP_MEMORY_SCOPE_AGENT);
    } else {
        // ================= consumer: attention combine for (b,q) ==============
        const int bq = blockIdx.x - NB * NK;
        const int b = bq >> 5;
        const int q = bq & 31;

        // per-(k,i) factor, 8-lane shfl product-reduce (verified r2)
        {
            const int k = t >> 3, i = t & 7;
            float qi  = query[(b*NQ + q)*8 + i];
            float ki  = key[(b*NK + k)*8 + i];
            float phi = attn_param[i] + ((i > 0) ? attn_param[8 + i - 1] : 0.f);
            float Th  = phi + qk_param[8 + i] - ki;
            float gam = qk_param[i] * 0.5f;
            c32 f = {  __cosf(gam) * __cosf((Th + qi)*0.5f),
                      -__sinf(gam) * __cosf((Th - qi)*0.5f) };
            #pragma unroll
            for (int off = 1; off < 8; off <<= 1) {
                c32 o2 = { __shfl_xor(f.x, off), __shfl_xor(f.y, off) };
                f = cmul(f, o2);
            }
            if (i == 0) {
                float h7 = attn_param[15] * 0.5f;
                float s7 = __sinf(h7), c7 = __cosf(h7);
                a0s[k] = make_float2(-s7*f.x, -s7*f.y);
                a1s[k] = make_float2( c7*f.x,  c7*f.y);
            }
        }
        __syncthreads();

        if (wv == 0 && ln < 32) {               // suffix product scan (verified r3)
            const int k = ln;
            c32 a0 = { a0s[k].x, a0s[k].y };
            c32 a1 = { a1s[k].x, a1s[k].y };
            c32 acc = a0;
            #pragma unroll
            for (int off = 1; off < 32; off <<= 1) {
                c32 v = { __shfl_down(acc.x, off), __shfl_down(acc.y, off) };
                if (k + off < 32) acc = cmul(acc, v);
            }
            c32 S = { __shfl_down(acc.x, 1), __shfl_down(acc.y, 1) };
            if (k == 31) { S.x = 1.f; S.y = 0.f; }
            c32 cf = cmul(S, a1);
            coeff[k] = make_float2(cf.x, cf.y);
            if (k == 0) totsh = make_float2(acc.x, acc.y);
        }
        if (t == 0) {                           // acquire-spin: batch b ready?
            while (__hip_atomic_load(&ctr[b*16], __ATOMIC_ACQUIRE,
                                     __HIP_MEMORY_SCOPE_AGENT) < 32u)
                __builtin_amdgcn_s_sleep(2);
        }
        __syncthreads();

        // v_new, probs
        {
            const int d = t;
            const float2* vb = vs + (size_t)(b * NK) * DIM;
            c32 vn = { 0.f, 0.f };
            #pragma unroll 8
            for (int k = 0; k < 32; ++k) {
                float2 cf = coeff[k];
                float2 v  = vb[k*DIM + d];
                vn.x += cf.x*v.x - cf.y*v.y;
                vn.y += cf.x*v.y + cf.y*v.x;
            }
            if (d == 0) { vn.x += totsh.x; vn.y += totsh.y; }
            prob[d] = vn.x*vn.x + vn.y*vn.y;
        }
        __syncthreads();

        // sign expectation per wire
        {
            const int gg = t >> 5, l = t & 31;
            float sp = 0.f, ss = 0.f;
            #pragma unroll
            for (int j2 = 0; j2 < 8; ++j2) {
                int d2 = l + 32*j2;
                float p = prob[d2];
                sp += p;
                ss += ((d2 >> (7 - gg)) & 1) ? -p : p;
            }
            #pragma unroll
            for (int off = 1; off < 32; off <<= 1) {
                sp += __shfl_xor(sp, off);
                ss += __shfl_xor(ss, off);
            }
            if (l == 0) out[(b*NQ + q)*8 + gg] = ss / sp;
        }
    }
}

extern "C" void kernel_launch(void* const* d_in, const int* in_sizes, int n_in,
                              void* d_out, int out_size, void* d_ws, size_t ws_size,
                              hipStream_t stream) {
    const float* query      = (const float*)d_in[0];
    const float* key        = (const float*)d_in[1];
    const float* value      = (const float*)d_in[2];
    const float* v_param    = (const float*)d_in[3];
    const float* qk_param   = (const float*)d_in[4];
    const float* attn_param = (const float*)d_in[5];

    float2*   vs  = (float2*)d_ws;                                  // 512 KB
    unsigned* ctr = (unsigned*)((char*)d_ws + (size_t)NB*NK*DIM*8); // +512 B
    float*    out = (float*)d_out;

    hipMemsetAsync(ctr, 0, NB * 64, stream);   // reset flags every call
    fused_kernel<<<2 * NB * NK, 256, 0, stream>>>(query, key, value, v_param,
                                                  qk_param, attn_param,
                                                  vs, ctr, out);
}

// Round 5
// 18.529 us; speedup vs baseline: 3.1508x; 2.3710x over previous
//
#include <hip/hip_runtime.h>
#include <math.h>

#define NB 8
#define NQ 32
#define NK 32
#define DIM 256

struct c32 { float x, y; };
__device__ __forceinline__ c32 cmul(c32 a, c32 b) {
    return { a.x*b.x - a.y*b.y, a.x*b.y + a.y*b.x };
}

// ---------------------------------------------------------------------------
// Compile-time GF(2) bookkeeping for the CNOT layers (verified rounds 3-4).
// ---------------------------------------------------------------------------
struct Maps { unsigned char m[6][8]; unsigned char r[6][8]; unsigned char fin[8]; };

constexpr unsigned gstep(int rep, unsigned y, int i) {
    int tgt = (i + 1 + rep) % 8;
    return y ^ (((y >> (7 - i)) & 1u) << (7 - tgt));
}
constexpr unsigned Lmap(int rep, unsigned x) {
    unsigned y = x;
    for (int i = 7; i >= 0; --i) y = gstep(rep, y, i);
    return y;
}
constexpr unsigned Linvmap(int rep, unsigned x) {
    unsigned y = x;
    for (int i = 0; i < 8; ++i) y = gstep(rep, y, i);
    return y;
}
constexpr Maps make_maps() {
    Maps mp{};
    unsigned Mc[8], Mic[8];
    for (int j2 = 0; j2 < 8; ++j2) { Mc[j2] = 1u << j2; Mic[j2] = 1u << j2; }
    for (int rep = 0; rep < 6; ++rep) {
        for (int bb = 0; bb < 8; ++bb) {
            mp.m[rep][bb] = (unsigned char)Mc[bb];
            unsigned row = 0;
            for (int k = 0; k < 8; ++k) row |= ((Mic[k] >> bb) & 1u) << k;
            mp.r[rep][bb] = (unsigned char)row;
        }
        unsigned nM[8], nMi[8];
        for (int j2 = 0; j2 < 8; ++j2) {
            unsigned v = Lmap(rep, 1u << j2), acc = 0;
            for (int k = 0; k < 8; ++k) if ((v >> k) & 1u) acc ^= Mc[k];
            nM[j2]  = acc;
            nMi[j2] = Linvmap(rep, Mic[j2]);
        }
        for (int j2 = 0; j2 < 8; ++j2) { Mc[j2] = nM[j2]; Mic[j2] = nMi[j2]; }
    }
    for (int j2 = 0; j2 < 8; ++j2) mp.fin[j2] = (unsigned char)Mic[j2];
    return mp;
}
constexpr Maps MAPS = make_maps();

// vs layout: float2 element index ((b*16 + (k>>1))*256 + d)*2 + (k&1)
// -> kernel2 lane d reads float4 (k pair) perfectly coalesced across lanes.

// ---------------------------------------------------------------------------
// Kernel 1: 256 blocks x 128 threads. Block s = b*32 + j.
//   wave 0: v-circuit sim for state (b, kst=j)  [barrier-free, virtual perms]
//   wave 1: attention coeffs for (b, q=j)       [factors + suffix scan]
// ---------------------------------------------------------------------------
__global__ __launch_bounds__(128) void k1_sim_coef(
        const float* __restrict__ query, const float* __restrict__ key,
        const float* __restrict__ value, const float* __restrict__ v_param,
        const float* __restrict__ qk_param, const float* __restrict__ attn_param,
        float2* __restrict__ vs, float2* __restrict__ coefg) {
    const int s  = blockIdx.x;
    const int b  = s >> 5;
    const int j  = s & 31;
    const int t  = threadIdx.x;
    const int ln = t & 63;

    if (t < 64) {
        // ================= wave 0: v-sim =================
        __shared__ float2 U[48][4];
        if (ln < 48) {                       // U matrices, built by this wave
            int rep = ln >> 3, w = ln & 7;
            float a   = v_param[(rep*3 + 0)*8 + w];
            float bb2 = v_param[(rep*3 + 1)*8 + w];
            float c   = v_param[(rep*3 + 2)*8 + w];
            float sb, cb;     __sincosf(bb2*0.5f, &sb, &cb);
            float sapc, capc; __sincosf((a + c)*0.5f, &sapc, &capc);
            float samc, camc; __sincosf((a - c)*0.5f, &samc, &camc);
            U[ln][0] = make_float2( cb*capc, -cb*sapc);
            U[ln][1] = make_float2(-sb*camc, -sb*samc);
            U[ln][2] = make_float2( sb*camc, -sb*samc);
            U[ln][3] = make_float2( cb*capc,  cb*sapc);
        }
        // initial RY product state
        float cv[8], sv[8];
        #pragma unroll
        for (int i = 0; i < 8; ++i) __sincosf(value[s*8 + i]*0.5f, &sv[i], &cv[i]);
        float common = 1.f;
        #pragma unroll
        for (int i = 0; i < 6; ++i)
            common *= ((ln >> (5 - i)) & 1) ? sv[i] : cv[i];
        float2 amp[4];
        amp[0] = make_float2(common*cv[6]*cv[7], 0.f);
        amp[1] = make_float2(common*cv[6]*sv[7], 0.f);
        amp[2] = make_float2(common*sv[6]*cv[7], 0.f);
        amp[3] = make_float2(common*sv[6]*sv[7], 0.f);

        // 48-gate chain, barrier-free (verified r3/r4)
        #pragma unroll
        for (int rep = 0; rep < 6; ++rep) {
            #pragma unroll
            for (int w = 0; w < 8; ++w) {
                const int g = rep*8 + w;
                const unsigned mm = MAPS.m[rep][7 - w];
                const unsigned rb = MAPS.r[rep][7 - w];
                const unsigned lm = mm >> 2;
                const unsigned sm = mm & 3;
                const float2 u00 = U[g][0], u01 = U[g][1];
                const float2 u10 = U[g][2], u11 = U[g][3];
                float2 P[4];
                if (sm == 0)      { P[0]=amp[0]; P[1]=amp[1]; P[2]=amp[2]; P[3]=amp[3]; }
                else if (sm == 1) { P[0]=amp[1]; P[1]=amp[0]; P[2]=amp[3]; P[3]=amp[2]; }
                else if (sm == 2) { P[0]=amp[2]; P[1]=amp[3]; P[2]=amp[0]; P[3]=amp[1]; }
                else              { P[0]=amp[3]; P[1]=amp[2]; P[2]=amp[1]; P[3]=amp[0]; }
                if (lm) {
                    #pragma unroll
                    for (int r2 = 0; r2 < 4; ++r2) {
                        P[r2].x = __shfl_xor(P[r2].x, (int)lm);
                        P[r2].y = __shfl_xor(P[r2].y, (int)lm);
                    }
                }
                const unsigned hx = __popc((unsigned)(ln << 2) & rb) & 1u;
                float2 na[4];
                #pragma unroll
                for (int r2 = 0; r2 < 4; ++r2) {
                    const bool h = (hx ^ (__popc((unsigned)r2 & rb) & 1u)) != 0u;
                    const float2 uo = h ? u11 : u00;
                    const float2 up = h ? u10 : u01;
                    na[r2].x = uo.x*amp[r2].x - uo.y*amp[r2].y + up.x*P[r2].x - up.y*P[r2].y;
                    na[r2].y = uo.x*amp[r2].y + uo.y*amp[r2].x + up.x*P[r2].y + up.y*P[r2].x;
                }
                #pragma unroll
                for (int r2 = 0; r2 < 4; ++r2) amp[r2] = na[r2];
            }
        }
        // scatter-store through Minv_final into k-pair-interleaved layout
        unsigned c0 = 0;
        #pragma unroll
        for (int kk = 0; kk < 6; ++kk)
            c0 ^= ((ln >> kk) & 1) ? (unsigned)MAPS.fin[kk + 2] : 0u;
        const int kst = j;
        float2* base = vs + ((size_t)(b*16 + (kst >> 1)) * 256) * 2 + (kst & 1);
        #pragma unroll
        for (int r2 = 0; r2 < 4; ++r2) {
            unsigned c = c0 ^ ((r2 & 1) ? (unsigned)MAPS.fin[0] : 0u)
                            ^ ((r2 & 2) ? (unsigned)MAPS.fin[1] : 0u);
            base[c*2] = amp[r2];
        }
    } else {
        // ================= wave 1: attention coefficients for (b, q=j) =========
        const int k = ln >> 1, h = ln & 1;
        c32 f = { 1.f, 0.f };
        #pragma unroll
        for (int ii = 0; ii < 4; ++ii) {
            const int i = h*4 + ii;
            float qi  = query[(b*NQ + j)*8 + i];
            float ki  = key[(b*NK + k)*8 + i];
            float phi = attn_param[i] + ((i > 0) ? attn_param[8 + i - 1] : 0.f);
            float Th  = phi + qk_param[8 + i] - ki;
            float gam = qk_param[i] * 0.5f;
            c32 fi = {  __cosf(gam) * __cosf((Th + qi)*0.5f),
                       -__sinf(gam) * __cosf((Th - qi)*0.5f) };
            f = cmul(f, fi);
        }
        {   // combine the two 4-factor halves
            c32 o2 = { __shfl_xor(f.x, 1), __shfl_xor(f.y, 1) };
            f = cmul(f, o2);
        }
        // compact: lane ln<32 grabs f for k=ln (lives at lane 2*ln)
        float fx = __shfl(f.x, 2*ln);
        float fy = __shfl(f.y, 2*ln);
        if (ln < 32) {
            const int kk = ln;
            float h7 = attn_param[15] * 0.5f;
            float s7 = __sinf(h7), c7 = __cosf(h7);
            c32 a0 = { -s7*fx, -s7*fy };
            c32 a1 = {  c7*fx,  c7*fy };
            c32 acc = a0;                      // backward inclusive product scan
            #pragma unroll
            for (int off = 1; off < 32; off <<= 1) {
                c32 v = { __shfl_down(acc.x, off), __shfl_down(acc.y, off) };
                if (kk + off < 32) acc = cmul(acc, v);
            }
            c32 S = { __shfl_down(acc.x, 1), __shfl_down(acc.y, 1) };
            if (kk == 31) { S.x = 1.f; S.y = 0.f; }
            c32 cf = cmul(S, a1);
            coefg[s*34 + kk] = make_float2(cf.x, cf.y);
            if (kk == 0) coefg[s*34 + 32] = make_float2(acc.x, acc.y);  // total
        }
    }
}

// ---------------------------------------------------------------------------
// Kernel 2: pure combine. 256 blocks (b,q) x 256 threads (d).
// ---------------------------------------------------------------------------
__global__ __launch_bounds__(256) void k2_combine(
        const float2* __restrict__ vs, const float2* __restrict__ coefg,
        float* __restrict__ out) {
    const int bq = blockIdx.x;
    const int b = bq >> 5;
    const int q = bq & 31;
    const int t = threadIdx.x;

    __shared__ float2 coefL[33];
    __shared__ float prob[256];

    if (t < 33) coefL[t] = coefg[bq*34 + t];
    __syncthreads();

    // lane d=t: 16 coalesced float4 loads (one k-pair each)
    {
        const float4* vb4 = reinterpret_cast<const float4*>(
            vs + ((size_t)b*16) * 512);          // b's panel, float2 units
        c32 vn = { 0.f, 0.f };
        #pragma unroll
        for (int k2 = 0; k2 < 16; ++k2) {
            float4 v2 = vb4[k2*256 + t];         // {k=2k2 (x,y), k=2k2+1 (x,y)}
            float2 cfa = coefL[2*k2], cfb = coefL[2*k2 + 1];
            vn.x += cfa.x*v2.x - cfa.y*v2.y + cfb.x*v2.z - cfb.y*v2.w;
            vn.y += cfa.x*v2.y + cfa.y*v2.x + cfb.x*v2.w + cfb.y*v2.z;
        }
        if (t == 0) { vn.x += coefL[32].x; vn.y += coefL[32].y; }
        prob[t] = vn.x*vn.x + vn.y*vn.y;
    }
    __syncthreads();

    // sign expectation per wire
    {
        const int gg = t >> 5, l = t & 31;
        float sp = 0.f, ss = 0.f;
        #pragma unroll
        for (int j2 = 0; j2 < 8; ++j2) {
            int d2 = l + 32*j2;
            float p = prob[d2];
            sp += p;
            ss += ((d2 >> (7 - gg)) & 1) ? -p : p;
        }
        #pragma unroll
        for (int off = 1; off < 32; off <<= 1) {
            sp += __shfl_xor(sp, off);
            ss += __shfl_xor(ss, off);
        }
        if (l == 0) out[(b*NQ + q)*8 + gg] = ss / sp;
    }
}

extern "C" void kernel_launch(void* const* d_in, const int* in_sizes, int n_in,
                              void* d_out, int out_size, void* d_ws, size_t ws_size,
                              hipStream_t stream) {
    const float* query      = (const float*)d_in[0];
    const float* key        = (const float*)d_in[1];
    const float* value      = (const float*)d_in[2];
    const float* v_param    = (const float*)d_in[3];
    const float* qk_param   = (const float*)d_in[4];
    const float* attn_param = (const float*)d_in[5];

    float2* vs    = (float2*)d_ws;                          // 512 KB
    float2* coefg = (float2*)((char*)d_ws + (size_t)512*1024);  // ~70 KB
    float*  out   = (float*)d_out;

    k1_sim_coef<<<NB*NK, 128, 0, stream>>>(query, key, value, v_param,
                                           qk_param, attn_param, vs, coefg);
    k2_combine<<<NB*NQ, 256, 0, stream>>>(vs, coefg, out);
}